// Round 13
// baseline (114.455 us; speedup 1.0000x reference)
//
#include <hip/hip_runtime.h>
#include <math.h>

#define Bb   48
#define Ww   100
#define Nn   1000
#define EMB  128
#define Hh   8
#define LL   101     // depot + 100 neighbors
#define LOCALK 100
#define TPB  128
#define PPB  2       // problems (waves) per block

typedef float f4v __attribute__((ext_vector_type(4)));
typedef _Float16 half2v __attribute__((ext_vector_type(2)));

// ---- workspace layout (float offsets)
#define WS_A     0       // [8][128]  a_h = (Wk q_h)/4
#define WS_PE    1024    // [101][128] pos-enc f32
#define WS_AC    13952   // [3][8] A_i[h] then [8] C[h]
#define WS_WVI   13984   // [4][128]  w_i·Wv[:,hd] (i=3 -> b)
#define WS_PEA   14496   // [8][101]  pe[l]·a_h
#define WS_PVT   15304   // f16 [101][128]  PVT[l][hd] = pe[l]·Wv[:,hd]
#define WS_GPT   21768   // f16 [128][128]  GPT[hd][l] = Wcw[hd]·pe[l], l>=101 -> 0
#define WS_CBPE  29960   // f32 [104]  Wcb·pe[l]
// end 30064 floats = 120 KB

// ---- per-problem LDS arena (bytes), regions time-multiplexed:
//  select : hist4[4][260]i32 @0 (4160), list[100]u64 @4288
//  attn   : attnh f16[8][104] @0 (1664)
//  out    : rowbuf f32[1000] @0 (4000)   (after u-loop)
//  stable : sel@5088 i32[104], perm@5504 u8[104], smk@5616 f32[101],
//           feat3@6032 f32[304], coef@7248 f32[24], uf@7360 f32[128],
//           mhf@7872 f32[128], cM@8384 f32[4]
#define AR_SIZE 8416
#define AR_LIST 4288
#define AR_SEL  5088
#define AR_PERM 5504
#define AR_SMK  5616
#define AR_F3   6032
#define AR_COEF 7248
#define AR_UF   7360
#define AR_MHF  7872
#define AR_CM   8384

#define WSYNC() do { __builtin_amdgcn_wave_barrier(); asm volatile("" ::: "memory"); } while (0)

__device__ __forceinline__ unsigned f2key(float x) {
    unsigned u = __float_as_uint(x);
    return (u & 0x80000000u) ? ~u : (u | 0x80000000u);
}
__device__ __forceinline__ float key2f(unsigned k) {
    unsigned u = (k & 0x80000000u) ? (k & 0x7fffffffu) : ~k;
    return __uint_as_float(u);
}

// ---- S1: q, a, A/C (block 0); pe + WVi (blocks 1..)
__global__ void setup1(const float* __restrict__ cur, const float* __restrict__ Wq,
                       const float* __restrict__ Wk, const float* __restrict__ iw,
                       const float* __restrict__ ib, const float* __restrict__ Wv,
                       float* __restrict__ ws) {
    const int t = threadIdx.x, b = blockIdx.x;
    if (b == 0) {
        __shared__ float qs[EMB];
        __shared__ float as_[Hh * EMB];
        if (t < EMB) {
            float acc = 0.f;
            for (int e = 0; e < EMB; ++e) acc += cur[e] * Wq[e * EMB + t];
            qs[t] = acc;
        }
        __syncthreads();
        for (int i = t; i < Hh * EMB; i += 256) {
            int h = i >> 7, e = i & 127;
            float acc = 0.f;
            for (int d = 0; d < 16; ++d) acc += Wk[e * EMB + h * 16 + d] * qs[h * 16 + d];
            acc *= 0.25f;
            as_[i] = acc; ws[WS_A + i] = acc;
        }
        __syncthreads();
        if (t < 32) {
            int i = t >> 3, h = t & 7;
            const float* src = (i == 0) ? iw : (i == 1) ? iw + EMB : (i == 2) ? iw + 2 * EMB : ib;
            float acc = 0.f;
            for (int e = 0; e < EMB; ++e) acc += src[e] * as_[h * EMB + e];
            ws[WS_AC + t] = acc;
        }
    } else {
        int base = (b - 1) * 256 + t;
        const float kneg = -0.14619587891040738f;  // -ln(10000)/63
        if (base < LL * EMB) {
            int l = base >> 7, c = base & 127, ic = c & 63;
            float inv = expf((float)ic * kneg);
            float v = (float)l * inv;
            ws[WS_PE + base] = (c < 64) ? sinf(v) : cosf(v);
        } else if (base < LL * EMB + 512) {
            int j = base - LL * EMB;
            int iv = j >> 7, hd = j & 127;
            const float* src = (iv == 0) ? iw : (iv == 1) ? iw + EMB : (iv == 2) ? iw + 2 * EMB : ib;
            float acc = 0.f;
            for (int e = 0; e < EMB; ++e) acc += src[e] * Wv[e * EMB + hd];
            ws[WS_WVI + j] = acc;
        }
    }
}

// ---- S2: PVT f16, GPT f16 (zero-padded), PEA, CBPE
__global__ void setup2(const float* __restrict__ Wv, const float* __restrict__ Wcw,
                       const float* __restrict__ Wcb, float* __restrict__ ws) {
    int idx = blockIdx.x * 256 + threadIdx.x;
    if (idx < 12928) {                               // PVT[l][hd]
        int l = idx >> 7, hd = idx & 127;
        const float* pr = ws + WS_PE + l * EMB;
        float acc = 0.f;
        for (int e = 0; e < EMB; ++e) acc += pr[e] * Wv[e * EMB + hd];
        ((_Float16*)(ws + WS_PVT))[idx] = (_Float16)acc;
    } else if (idx < 12928 + 16384) {                // GPT[hd][l], stride 128
        int j = idx - 12928;
        int hd = j >> 7, l = j & 127;
        float acc = 0.f;
        if (l < LL) {
            const float* wr = Wcw + hd * EMB;
            const float* pr = ws + WS_PE + l * EMB;
            for (int e = 0; e < EMB; ++e) acc += wr[e] * pr[e];
        }
        ((_Float16*)(ws + WS_GPT))[j] = (_Float16)acc;
    } else if (idx < 29312 + 808) {                  // PEA[h][l]
        int j = idx - 29312;
        int h = j / LL, l = j - h * LL;
        const float* pr = ws + WS_PE + l * EMB;
        const float* ar = ws + WS_A + h * EMB;
        float acc = 0.f;
        for (int e = 0; e < EMB; ++e) acc += pr[e] * ar[e];
        ws[WS_PEA + j] = acc;
    } else if (idx < 30120 + 104) {                  // cbpe[l]
        int l = idx - 30120;
        float acc = 0.f;
        if (l < LL) {
            const float* pr = ws + WS_PE + l * EMB;
            for (int e = 0; e < EMB; ++e) acc += Wcb[e] * pr[e];
        }
        ws[WS_CBPE + l] = acc;
    }
}

// ================= fused main kernel: one problem per wave =================
__global__ __launch_bounds__(TPB, 6) void main_kernel(
    const float* __restrict__ dist,
    const float* __restrict__ xy,
    const float* __restrict__ ndem,
    const float* __restrict__ ninf,
    const float* __restrict__ iw,
    const float* __restrict__ ib,
    const float* __restrict__ Wcw,
    const float* __restrict__ Wcb,
    const float* __restrict__ ws,
    float* __restrict__ out) {

    __shared__ __align__(16) char smem[PPB][AR_SIZE];
    __shared__ __align__(16) float sPEA[Hh * LL + 32];

    const int tid  = threadIdx.x;
    const int w    = tid >> 6;
    const int lane = tid & 63;
    const int bid  = blockIdx.x;
    const int bw   = ((bid & 7) * 300 + (bid >> 3)) * PPB + w;   // XCD-bijective

    for (int i = tid; i < Hh * LL + 32; i += TPB)
        sPEA[i] = (i < Hh * LL) ? ws[WS_PEA + i] : ws[WS_AC + (i - Hh * LL)];
    __syncthreads();
    const float* sAC = sPEA + Hh * LL;

    char* A = smem[w];
    int*                hist4 = (int*)A;                      // [4][260]
    _Float16*           attnh = (_Float16*)A;                 // [8][104] (after select)
    float*              rowbuf = (float*)A;                   // [1000]  (after u-loop)
    unsigned long long* list  = (unsigned long long*)(A + AR_LIST);
    int*                sel   = (int*)(A + AR_SEL);
    unsigned char*      perm  = (unsigned char*)(A + AR_PERM);
    float*              smk   = (float*)(A + AR_SMK);
    float*              feat3 = (float*)(A + AR_F3);
    float*              coefA = (float*)(A + AR_COEF);
    float*              uf    = (float*)(A + AR_UF);
    float*              mhf   = (float*)(A + AR_MHF);
    float*              cM    = (float*)(A + AR_CM);

    const float* distRow = dist + (size_t)bw * Nn;
    const float* maskRow = ninf + (size_t)bw * Nn;
    const float* xyRow   = xy   + (size_t)bw * Nn * 2;
    const float* demRow  = ndem + (size_t)bw * Nn;

    // ---- phase 0: stream dist+mask (coalesced float4), mask kept in regs
    float dvf[16], mkf[16];
    {
        float4 dv[4], mv[4];
        #pragma unroll
        for (int c = 0; c < 4; ++c) {
            int n0 = c * 256 + lane * 4;
            if (n0 < Nn) {
                dv[c] = *(const float4*)(distRow + n0);
                mv[c] = *(const float4*)(maskRow + n0);
            } else {
                dv[c] = make_float4(0.f, 0.f, 0.f, 0.f);
                mv[c] = make_float4(0.f, 0.f, 0.f, 0.f);
            }
        }
        #pragma unroll
        for (int k = 0; k < 5; ++k) {
            int idx = lane + 64 * k;
            if (idx < 260) ((int4*)hist4)[idx] = make_int4(0, 0, 0, 0);
        }
        #pragma unroll
        for (int c = 0; c < 4; ++c) {
            dvf[4*c+0] = dv[c].x; dvf[4*c+1] = dv[c].y; dvf[4*c+2] = dv[c].z; dvf[4*c+3] = dv[c].w;
            mkf[4*c+0] = mv[c].x; mkf[4*c+1] = mv[c].y; mkf[4*c+2] = mv[c].z; mkf[4*c+3] = mv[c].w;
        }
    }
    unsigned long long rk[16];
    #pragma unroll
    for (int r = 0; r < 16; ++r) {
        int n = (r >> 2) * 256 + lane * 4 + (r & 3);
        unsigned long long kv = ~0ull;
        if (n >= 1 && n < Nn) {
            float de = dvf[r] - mkf[r];
            kv = ((unsigned long long)f2key(de) << 32) | (unsigned)n;
        }
        rk[r] = kv;
    }
    WSYNC();

    // ---- radix select (MSB-first, 4 bank-staggered sub-hists), wave-local
    unsigned long long prefix = 0;
    int shift = 56;
    int remRank = 99;
    const unsigned long long ltm = (1ull << lane) - 1ull;
    const int g0 = (lane >> 4) * 260;
    for (int round = 0; round < 8; ++round) {
        shift = 56 - 8 * round;
        #pragma unroll
        for (int r = 0; r < 16; ++r) {
            unsigned long long kv = rk[r];
            bool in = (kv != ~0ull) &&
                      (round == 0 || (kv >> (shift + 8)) == (prefix >> (shift + 8)));
            if (in) atomicAdd(&hist4[g0 + (int)((kv >> shift) & 0xffull)], 1);
        }
        WSYNC();
        int4 h0 = *(int4*)&hist4[0 * 260 + 4 * lane];
        int4 h1 = *(int4*)&hist4[1 * 260 + 4 * lane];
        int4 h2 = *(int4*)&hist4[2 * 260 + 4 * lane];
        int4 h3 = *(int4*)&hist4[3 * 260 + 4 * lane];
        int4 z = make_int4(0, 0, 0, 0);
        *(int4*)&hist4[0 * 260 + 4 * lane] = z;
        *(int4*)&hist4[1 * 260 + 4 * lane] = z;
        *(int4*)&hist4[2 * 260 + 4 * lane] = z;
        *(int4*)&hist4[3 * 260 + 4 * lane] = z;
        int cx = h0.x + h1.x + h2.x + h3.x;
        int cy = h0.y + h1.y + h2.y + h3.y;
        int cz = h0.z + h1.z + h2.z + h3.z;
        int cw = h0.w + h1.w + h2.w + h3.w;
        int s = cx + cy + cz + cw;
        int incl = s;
        #pragma unroll
        for (int o = 1; o < 64; o <<= 1) { int t = __shfl_up(incl, o, 64); if (lane >= o) incl += t; }
        int e0 = incl - s;
        int e1 = e0 + cx, e2 = e1 + cy, e3 = e2 + cz;
        int bc = -1, ec = 0, cc = 0;
        if (cx > 0 && remRank >= e0 && remRank < e1)      { bc = 4*lane+0; ec = e0; cc = cx; }
        if (cy > 0 && remRank >= e1 && remRank < e2)      { bc = 4*lane+1; ec = e1; cc = cy; }
        if (cz > 0 && remRank >= e2 && remRank < e3)      { bc = 4*lane+2; ec = e2; cc = cz; }
        if (cw > 0 && remRank >= e3 && remRank < e3 + cw) { bc = 4*lane+3; ec = e3; cc = cw; }
        unsigned long long fm = __ballot(bc >= 0);
        int srcl = __ffsll((unsigned long long)fm) - 1;
        bc = __shfl(bc, srcl, 64); ec = __shfl(ec, srcl, 64); cc = __shfl(cc, srcl, 64);
        prefix |= ((unsigned long long)(unsigned)bc) << shift;
        remRank -= ec;
        if (cc == 1) break;
    }
    unsigned long long pk = 0; bool pf = false;
    #pragma unroll
    for (int r = 0; r < 16; ++r)
        if ((rk[r] >> shift) == (prefix >> shift)) { pk = rk[r]; pf = true; }
    {
        unsigned long long fm = __ballot(pf);
        int srcl = __ffsll((unsigned long long)fm) - 1;
        pk = __shfl(pk, srcl, 64);
    }
    const unsigned long long pivot = pk;

    // ---- ballot-compact the 100 keys <= pivot into list (p-order)
    int cnt_run = 0;
    #pragma unroll
    for (int r = 0; r < 16; ++r) {
        bool p = rk[r] <= pivot;
        unsigned long long m = __ballot(p);
        if (p) list[cnt_run + (int)__popcll(m & ltm)] = rk[r];
        cnt_run += (int)__popcll(m);
    }
    WSYNC();

    // ---- issue xy/ndem streams NOW (latency hides under the rank loop)
    float xs[16], ys[16], dd[16];
    {
        #pragma unroll
        for (int c = 0; c < 4; ++c) {
            int n0 = c * 256 + lane * 4;
            float4 a0, a1, d0;
            if (n0 < Nn) {
                a0 = *(const float4*)(xyRow + 2 * n0);
                a1 = *(const float4*)(xyRow + 2 * n0 + 4);
                d0 = *(const float4*)(demRow + n0);
            } else {
                a0 = a1 = d0 = make_float4(0.f, 0.f, 0.f, 0.f);
            }
            xs[4*c+0] = a0.x; ys[4*c+0] = a0.y;
            xs[4*c+1] = a0.z; ys[4*c+1] = a0.w;
            xs[4*c+2] = a1.x; ys[4*c+2] = a1.y;
            xs[4*c+3] = a1.z; ys[4*c+3] = a1.w;
            dd[4*c+0] = d0.x; dd[4*c+1] = d0.y; dd[4*c+2] = d0.z; dd[4*c+3] = d0.w;
        }
    }

    // ---- parallel rank: perm[p] = rank+1 ; norm max
    {
        unsigned long long kv0 = list[lane];
        const bool has1 = lane < (LOCALK - 64);
        unsigned long long kv1 = has1 ? list[lane + 64] : ~0ull;
        int r0 = 0, r1 = 0;
        #pragma unroll 4
        for (int j = 0; j < LOCALK; ++j) {
            unsigned long long lv = list[j];
            r0 += (lv < kv0);
            r1 += (lv < kv1);
        }
        float v0 = key2f((unsigned)(kv0 >> 32));
        float dvm = isinf(v0) ? 0.f : v0;
        perm[lane] = (unsigned char)(r0 + 1);
        if (has1) {
            float v1 = key2f((unsigned)(kv1 >> 32));
            perm[lane + 64] = (unsigned char)(r1 + 1);
            dvm = fmaxf(dvm, isinf(v1) ? 0.f : v1);
        }
        #pragma unroll
        for (int o = 32; o > 0; o >>= 1) dvm = fmaxf(dvm, __shfl_xor(dvm, o, 64));
        const float nmax = dvm;
        const bool  norm_on = (nmax != 0.f);
        const float nfac = nmax + 1e-6f;
        WSYNC();

        // ---- scatter features from registers (no global gather)
        int crun = 0;
        #pragma unroll
        for (int r = 0; r < 16; ++r) {
            unsigned long long kv = rk[r];
            bool p = kv <= pivot;
            unsigned long long m = __ballot(p);
            int pos = crun + (int)__popcll(m & ltm);
            crun += (int)__popcll(m);
            if (p) {
                int rnk = perm[pos];
                float val = key2f((unsigned)(kv >> 32));
                bool infm = isinf(val);
                float fx = infm ? 0.f : xs[r];
                float fy = infm ? 0.f : ys[r];
                float fd = infm ? 0.f : dd[r];
                if (norm_on) { fx /= nfac; fy /= nfac; }
                int n = (int)(kv & 0xffffffu);
                feat3[rnk] = fx; feat3[101 + rnk] = fy; feat3[202 + rnk] = fd;
                smk[rnk] = mkf[r];
                sel[rnk] = n | (infm ? 0x4000 : 0);
            }
        }
        if (lane == 0) {
            feat3[0] = 0.f; feat3[101] = 0.f; feat3[202] = 0.f; feat3[303] = 0.f;
            smk[0] = mkf[0];
            sel[0] = 0x4000;
        }
    }
    WSYNC();

    // ---- fused scores + softmax + coef: 8 lanes per head
    const int h = lane >> 3, ln8 = lane & 7;
    {
        const float A0 = sAC[h], A1 = sAC[8 + h], A2 = sAC[16 + h], Cc = sAC[24 + h];
        const float* pea = sPEA + h * LL;
        float ev[13];
        float mx = -INFINITY;
        #pragma unroll
        for (int k = 0; k < 13; ++k) {
            int l = ln8 + 8 * k;
            float sv = -INFINITY;
            if (l < LL)
                sv = feat3[l] * A0 + feat3[101 + l] * A1 + feat3[202 + l] * A2
                   + Cc + pea[l] + smk[l];
            ev[k] = sv;
            mx = fmaxf(mx, sv);
        }
        #pragma unroll
        for (int o = 1; o < 8; o <<= 1) mx = fmaxf(mx, __shfl_xor(mx, o, 64));
        float sm = 0.f;
        #pragma unroll
        for (int k = 0; k < 13; ++k) {
            int l = ln8 + 8 * k;
            float e = (l < LL) ? __expf(ev[k] - mx) : 0.f;
            ev[k] = e; sm += e;
        }
        #pragma unroll
        for (int o = 1; o < 8; o <<= 1) sm += __shfl_xor(sm, o, 64);
        const float ainv = 1.f / sm;
        float c0 = 0.f, c1 = 0.f, c2 = 0.f;
        #pragma unroll
        for (int k = 0; k < 13; ++k) {
            int l = ln8 + 8 * k;                 // l <= 103
            float at = ev[k] * ainv;
            attnh[h * 104 + l] = (_Float16)at;   // zeros at 101..103
            if (l < LL) {
                c0 += at * feat3[l]; c1 += at * feat3[101 + l]; c2 += at * feat3[202 + l];
            }
        }
        #pragma unroll
        for (int o = 1; o < 8; o <<= 1) {
            c0 += __shfl_xor(c0, o, 64); c1 += __shfl_xor(c1, o, 64); c2 += __shfl_xor(c2, o, 64);
        }
        if (ln8 == 0) { coefA[h * 3 + 0] = c0; coefA[h * 3 + 1] = c1; coefA[h * 3 + 2] = c2; }
    }
    WSYNC();

    // ---- u[hd] for hd = {2*lane, 2*lane+1}: broadcast attn row × contiguous PVT cols
    {
        const _Float16* pv = (const _Float16*)(ws + WS_PVT) + 2 * lane;
        const _Float16* arow = attnh + h * 104;    // h == (2*lane)>>4 == lane>>3
        float u0 = 0.f, u1 = 0.f;
        #pragma unroll 4
        for (int l = 0; l < LL; ++l) {
            float a = (float)arow[l];
            half2v p = *(const half2v*)(pv + (size_t)l * 128);
            u0 += a * (float)p.x;
            u1 += a * (float)p.y;
        }
        float cc0 = coefA[h * 3 + 0], cc1 = coefA[h * 3 + 1], cc2 = coefA[h * 3 + 2];
        float2 w0 = *(const float2*)(ws + WS_WVI + 2 * lane);
        float2 w1 = *(const float2*)(ws + WS_WVI + 128 + 2 * lane);
        float2 w2 = *(const float2*)(ws + WS_WVI + 256 + 2 * lane);
        float2 w3 = *(const float2*)(ws + WS_WVI + 384 + 2 * lane);
        u0 += cc0 * w0.x + cc1 * w1.x + cc2 * w2.x + w3.x;
        u1 += cc0 * w0.y + cc1 * w1.y + cc2 * w2.y + w3.y;
        *(float2*)(uf + 2 * lane) = make_float2(u0, u1);
    }
    WSYNC();

    // ---- mh[e] for e = {2*lane, 2*lane+1}: broadcast uf × contiguous Wcw rows
    {
        float2 wb = *(const float2*)(Wcb + 2 * lane);
        float m0 = wb.x, m1 = wb.y;
        const float* wc = Wcw + 2 * lane;
        #pragma unroll 4
        for (int hd = 0; hd < EMB; ++hd) {
            float uu = uf[hd];
            float2 wv = *(const float2*)(wc + (size_t)hd * 128);
            m0 += uu * wv.x; m1 += uu * wv.y;
        }
        *(float2*)(mhf + 2 * lane) = make_float2(m0, m1);
    }
    WSYNC();

    // ---- coefM[g] = mh . {w0,w1,w2,b} ; zero rowbuf (attnh/hist/list dead)
    {
        int g = lane & 3;
        const float* src = (g == 0) ? iw : (g == 1) ? iw + EMB : (g == 2) ? iw + 2 * EMB : ib;
        float v = 0.f;
        #pragma unroll
        for (int j = 0; j < 8; ++j) {
            int e = (lane >> 2) + 16 * j;
            v += mhf[e] * src[e];
        }
        v += __shfl_xor(v, 4, 64); v += __shfl_xor(v, 8, 64);
        v += __shfl_xor(v, 16, 64); v += __shfl_xor(v, 32, 64);
        if (lane < 4) cM[lane] = v;
    }
    {
        float4 z = make_float4(0.f, 0.f, 0.f, 0.f);
        ((float4*)rowbuf)[lane] = z;
        ((float4*)rowbuf)[lane + 64] = z;
        ((float4*)rowbuf)[lane + 128] = z;
        if (lane < 58) ((float4*)rowbuf)[lane + 192] = z;
    }
    WSYNC();

    // ---- score2: broadcast uf × contiguous GPT rows; scatter into rowbuf
    {
        const _Float16* gp = (const _Float16*)(ws + WS_GPT);
        float s0 = 0.f, s1 = 0.f;
        #pragma unroll 4
        for (int hd = 0; hd < EMB; ++hd) {
            float uu = uf[hd];
            s0 += uu * (float)gp[hd * 128 + lane];
            s1 += uu * (float)gp[hd * 128 + lane + 64];   // zero-padded l>=101
        }
        const float scale = 0.08838834764831845f;
        {
            int t = lane;
            float base = feat3[t] * cM[0] + feat3[101 + t] * cM[1]
                       + feat3[202 + t] * cM[2] + cM[3] + ws[WS_CBPE + t];
            rowbuf[sel[t] & 0xFFF] = (base + s0) * scale;
        }
        if (lane + 64 < LL) {
            int t = lane + 64;
            float base = feat3[t] * cM[0] + feat3[101 + t] * cM[1]
                       + feat3[202 + t] * cM[2] + cM[3] + ws[WS_CBPE + t];
            rowbuf[sel[t] & 0xFFF] = (base + s1) * scale;
        }
    }
    WSYNC();

    // ---- stream the row out (nontemporal stores)
    float* outRow = out + (size_t)bw * Nn;
    #pragma unroll
    for (int c = 0; c < 4; ++c) {
        int i = lane + 64 * c;
        if (i < 250) {
            f4v v = *(const f4v*)(rowbuf + 4 * i);
            __builtin_nontemporal_store(v, (f4v*)(outRow + 4 * i));
        }
    }
}

extern "C" void kernel_launch(void* const* d_in, const int* in_sizes, int n_in,
                              void* d_out, int out_size, void* d_ws, size_t ws_size,
                              hipStream_t stream) {
    // 0 theta, 1 dist, 2 xy, 3 norm_demand, 4 ninf_mask,
    // 5 init_w, 6 init_b, 7 cur_token, 8 Wq, 9 Wk, 10 Wv, 11 Wc_w, 12 Wc_b
    const float* dist  = (const float*)d_in[1];
    const float* xy    = (const float*)d_in[2];
    const float* ndem  = (const float*)d_in[3];
    const float* ninf  = (const float*)d_in[4];
    const float* initw = (const float*)d_in[5];
    const float* initb = (const float*)d_in[6];
    const float* cur   = (const float*)d_in[7];
    const float* Wq    = (const float*)d_in[8];
    const float* Wk    = (const float*)d_in[9];
    const float* Wv    = (const float*)d_in[10];
    const float* Wcw   = (const float*)d_in[11];
    const float* Wcb   = (const float*)d_in[12];
    float* out = (float*)d_out;
    float* ws  = (float*)d_ws;

    hipLaunchKernelGGL(setup1, dim3(56),  dim3(256), 0, stream, cur, Wq, Wk, initw, initb, Wv, ws);
    hipLaunchKernelGGL(setup2, dim3(119), dim3(256), 0, stream, Wv, Wcw, Wcb, ws);
    hipLaunchKernelGGL(main_kernel, dim3(Bb * Ww / PPB), dim3(TPB), 0, stream,
                       dist, xy, ndem, ninf, initw, initb, Wcw, Wcb, ws, out);
}